// Round 6
// baseline (1293.473 us; speedup 1.0000x reference)
//
#include <hip/hip_runtime.h>

#define CDIV(a,b) (((a)+(b)-1)/(b))

typedef __attribute__((ext_vector_type(8))) short bf16x8;
typedef __attribute__((ext_vector_type(4))) float floatx4;

__device__ __forceinline__ ushort f2bf(float x) {
    unsigned u = __float_as_uint(x);
    return (ushort)((u + 0x7fffu + ((u >> 16) & 1u)) >> 16);   // RNE
}
__device__ __forceinline__ float bflo(unsigned v) { return __uint_as_float(v << 16); }
__device__ __forceinline__ float bfhi(unsigned v) { return __uint_as_float(v & 0xffff0000u); }

__device__ __forceinline__ void load_lds16(const ushort* g, ushort* l) {
    __builtin_amdgcn_global_load_lds(
        (const __attribute__((address_space(1))) void*)g,
        (__attribute__((address_space(3))) void*)l, 16, 0, 0);
}

// B LDS tile: [128 rows][64 bf16], XOR-swizzled within each 64-col block:
//   LDS[row][c] holds element (row, kb*64 + (c ^ ((row&7)<<3)))
// fill_w5 pre-permutes the global B panels the same way, so linear
// global_load_lds staging lands swizzled; ds_read applies the same XOR ->
// conflict-free fragment reads (T2). A never touches LDS (direct global frags).

// ---------------- utility kernels ----------------

__global__ void zero_f4(float4* __restrict__ p, long long n4) {
    long long i = blockIdx.x * 256LL + threadIdx.x;
    if (i < n4) p[i] = make_float4(0.f, 0.f, 0.f, 0.f);
}

// One layer's 5 weight blocks, transposed bf16, K-swizzled. sections (blockIdx.y):
// 0: BsT col0=0   rel0 | 1: BsT col0=N rel2 | 2: BsT col0=2N loop | 3: BdT col0=0 rel1 | 4: BdT col0=N loop
__global__ void fill_w5(ushort* __restrict__ BsT, ushort* __restrict__ BdT,
                        const float* __restrict__ basis, const float* __restrict__ loopw,
                        const float* __restrict__ coeff, int K, int N, long long KN) {
    long long i = blockIdx.x * 256LL + threadIdx.x;
    if (i >= KN) return;
    int k = (int)(i % K), n = (int)(i / K);
    int sec = blockIdx.y;
    float val;
    if (sec == 2 || sec == 4) {
        val = loopw[(size_t)k * N + n];
    } else {
        int r = (sec == 0) ? 0 : (sec == 1) ? 2 : 1;
        val = coeff[2 * r] * basis[(size_t)k * N + n] + coeff[2 * r + 1] * basis[KN + (size_t)k * N + n];
    }
    ushort* dst = (sec < 3) ? BsT : BdT;
    int col0 = (sec == 0) ? 0 : (sec == 1) ? N : (sec == 2) ? 2 * N : (sec == 3) ? 0 : N;
    int nn = col0 + n;
    dst[(size_t)nn * K + (k & ~63) + ((k & 63) ^ ((nn & 7) << 3))] = f2bf(val);
}

// ---------------- CSR build ----------------

__global__ void accum_deg_all(const int* __restrict__ dss, const int* __restrict__ dds,
                              const int* __restrict__ dsd, int nss, int nds, int nsd,
                              int NS, int* __restrict__ deg) {
    int i = blockIdx.x * 256 + threadIdx.x;
    if (i < nss) atomicAdd(&deg[dss[i]], 1);
    else if (i < nss + nds) atomicAdd(&deg[NS + dds[i - nss]], 1);
    else if (i < nss + nds + nsd) atomicAdd(&deg[2 * NS + dsd[i - nss - nds]], 1);
}

__global__ void scan_p1(const int* __restrict__ deg, int n, int* __restrict__ bsum) {
    __shared__ int sd[256];
    int blk = blockIdx.x, tid = threadIdx.x;
    int i0 = blk * 1024 + tid * 4;
    int s = 0;
#pragma unroll
    for (int j = 0; j < 4; ++j) if (i0 + j < n) s += deg[i0 + j];
    sd[tid] = s; __syncthreads();
    for (int o = 128; o; o >>= 1) {
        if (tid < o) sd[tid] += sd[tid + o];
        __syncthreads();
    }
    if (tid == 0) bsum[blk] = sd[0];
}

__global__ void scan_p2(int* __restrict__ bsum, int nb, int* __restrict__ rowptr, int ntot, int etot) {
    __shared__ int sd[256];
    int tid = threadIdx.x;
    int v = (tid < nb) ? bsum[tid] : 0;
    sd[tid] = v; __syncthreads();
    for (int o = 1; o < 256; o <<= 1) {
        int t = (tid >= o) ? sd[tid - o] : 0;
        __syncthreads();
        sd[tid] += t;
        __syncthreads();
    }
    if (tid < nb) bsum[tid] = sd[tid] - v;
    if (tid == 0) rowptr[ntot] = etot;
}

__global__ void scan_p3(const int* __restrict__ deg, int n, const int* __restrict__ bsum,
                        int* __restrict__ rowptr) {
    __shared__ int sd[256];
    int blk = blockIdx.x, tid = threadIdx.x;
    int i0 = blk * 1024 + tid * 4;
    int v[4]; int s = 0;
#pragma unroll
    for (int j = 0; j < 4; ++j) { v[j] = (i0 + j < n) ? deg[i0 + j] : 0; s += v[j]; }
    sd[tid] = s; __syncthreads();
    for (int o = 1; o < 256; o <<= 1) {
        int t = (tid >= o) ? sd[tid - o] : 0;
        __syncthreads();
        sd[tid] += t;
        __syncthreads();
    }
    int excl = bsum[blk] + sd[tid] - s;
#pragma unroll
    for (int j = 0; j < 4; ++j) {
        if (i0 + j < n) rowptr[i0 + j] = excl;
        excl += v[j];
    }
}

__global__ void fill_csr_all(const int* __restrict__ sss, const int* __restrict__ dss,
                             const int* __restrict__ sds, const int* __restrict__ dds,
                             const int* __restrict__ ssd, const int* __restrict__ dsd,
                             int nss, int nds, int nsd, int NS,
                             const int* __restrict__ rowptr, int* __restrict__ fill,
                             int* __restrict__ col) {
    int i = blockIdx.x * 256 + threadIdx.x;
    int d, s;
    if (i < nss) { d = dss[i]; s = sss[i]; }
    else if (i < nss + nds) { int j = i - nss; d = NS + dds[j]; s = sds[j]; }
    else if (i < nss + nds + nsd) { int j = i - nss - nds; d = 2 * NS + dsd[j]; s = ssd[j]; }
    else return;
    int p = rowptr[d] + atomicAdd(&fill[d], 1);
    col[p] = s;
}

// ---------------- MFMA GEMM: C[M,N] bf16 = A[M,K] @ Bt[N,K]^T ----------------
// A is read DIRECTLY from global into MFMA fragments (8 contiguous k-elems per
// lane): AF32=true -> 2x float4 + cvt; AF32=false -> one 16B bf16 read.
// B: pre-swizzled global, double-buffered global_load_lds, ONE barrier/K-step:
//   barrier -> issue stage B[t+1] -> ds_read B[t] frags -> A-direct + MFMA.
// XCD-bijective 1-D grid swizzle (m204) keeps an A panel on one XCD's L2.
template<bool AF32>
__global__ __launch_bounds__(256) void gemm_any(
    const void* __restrict__ Araw, const ushort* __restrict__ Bt, ushort* __restrict__ C,
    int M, int K, int N, int BNX) {
    const int nwg = gridDim.x;
    const int orig = blockIdx.x;
    const int q = nwg >> 3, r = nwg & 7;
    const int xcd = orig & 7, idx = orig >> 3;
    const int wg = (xcd < r ? xcd * (q + 1) : r * (q + 1) + (xcd - r) * q) + idx;
    const int bn = (wg % BNX) * 128;
    const long long bm = (long long)(wg / BNX) * 128LL;

    __shared__ ushort Bs[2][128 * 64];
    const int tid = threadIdx.x;
    const int lane = tid & 63, wave = tid >> 6;
    const int mo = (wave & 1) * 64, no = (wave >> 1) * 64;
    const int l15 = lane & 15, quad = lane >> 4;
    const int srow = wave * 8 + (lane >> 3);   // staging row within 32-row group
    const int bch = (lane & 7) * 8;            // staging chunk (ushorts) within 64
    floatx4 acc[4][4] = {};

    // per-mt A row base (clamped), in elements
    size_t aoff[4];
#pragma unroll
    for (int mt = 0; mt < 4; ++mt) {
        long long ar = bm + mo + mt * 16 + l15;
        if (ar >= M) ar = M - 1;
        aoff[mt] = (size_t)ar * K;
    }

    auto stageB = [&](int k0, int buf) {
#pragma unroll
        for (int t = 0; t < 4; ++t) {
            int row = t * 32 + srow;
            load_lds16(Bt + (size_t)(bn + row) * K + k0 + bch,
                       Bs[buf] + (t * 32 + wave * 8) * 64);
        }
    };

    stageB(0, 0);
    int cur = 0;
    for (int k0 = 0; k0 < K; k0 += 64) {
        __syncthreads();                    // B[k0] staged (drains vmcnt)
        if (k0 + 64 < K) stageB(k0 + 64, cur ^ 1);   // prefetch under compute
        // B fragments (XOR-swizzled, conflict-free)
        bf16x8 bfr[2][4];
#pragma unroll
        for (int h = 0; h < 2; ++h)
#pragma unroll
            for (int nt = 0; nt < 4; ++nt) {
                int row = no + nt * 16 + l15;
                bfr[h][nt] = *(const bf16x8*)(Bs[cur] + row * 64 + ((h * 32 + quad * 8) ^ ((row & 7) << 3)));
            }
        // A direct-from-global fragments + MFMA
#pragma unroll
        for (int h = 0; h < 2; ++h) {
#pragma unroll
            for (int mt = 0; mt < 4; ++mt) {
                bf16x8 af;
                if (AF32) {
                    const float* ap = (const float*)Araw + aoff[mt] + k0 + h * 32 + quad * 8;
                    float4 p0 = *(const float4*)ap;
                    float4 p1 = *(const float4*)(ap + 4);
                    unsigned w0 = (unsigned)f2bf(p0.x) | ((unsigned)f2bf(p0.y) << 16);
                    unsigned w1 = (unsigned)f2bf(p0.z) | ((unsigned)f2bf(p0.w) << 16);
                    unsigned w2 = (unsigned)f2bf(p1.x) | ((unsigned)f2bf(p1.y) << 16);
                    unsigned w3 = (unsigned)f2bf(p1.z) | ((unsigned)f2bf(p1.w) << 16);
                    uint4 packed = make_uint4(w0, w1, w2, w3);
                    af = *(const bf16x8*)&packed;
                } else {
                    af = *(const bf16x8*)((const ushort*)Araw + aoff[mt] + k0 + h * 32 + quad * 8);
                }
#pragma unroll
                for (int nt = 0; nt < 4; ++nt)
                    acc[mt][nt] = __builtin_amdgcn_mfma_f32_16x16x32_bf16(af, bfr[h][nt], acc[mt][nt], 0, 0, 0);
            }
        }
        cur ^= 1;
    }
#pragma unroll
    for (int mt = 0; mt < 4; ++mt)
#pragma unroll
        for (int i = 0; i < 4; ++i) {
            long long row = bm + mo + mt * 16 + quad * 4 + i;
            if (row < M) {
#pragma unroll
                for (int nt = 0; nt < 4; ++nt)
                    C[row * (size_t)N + bn + no + nt * 16 + l15] = f2bf(acc[mt][nt][i]);
            }
        }
}

// ---------------- fused gather kernels (sent + doc merged) ----------------
// one wave per dst node; edge loops unrolled x4 for memory-level parallelism

__global__ __launch_bounds__(256) void gather_l1(
    const ushort* __restrict__ ys, const ushort* __restrict__ yd,
    const int* __restrict__ rowptr, const int* __restrict__ col,
    const float* __restrict__ bias, ushort* __restrict__ h1s, ushort* __restrict__ h1d,
    int NS, int ND) {
    int d = blockIdx.x * 4 + (threadIdx.x >> 6);
    int lane = threadIdx.x & 63;
    int cb = lane * 4;
    float b0 = bias[cb], b1 = bias[cb + 1], b2 = bias[cb + 2], b3 = bias[cb + 3];
    if (d < NS) {
        // ---- sent dst: mean_ss(ys[:,256:512]) + mean_ds(yd[:,0:256]) + ys[d,512:768] ----
        float a0 = 0, a1 = 0, a2 = 0, a3 = 0;
        int s0 = rowptr[d], s1 = rowptr[d + 1];
        int e = s0;
        for (; e + 4 <= s1; e += 4) {
            int sA = col[e], sB = col[e + 1], sC = col[e + 2], sD = col[e + 3];
            uint2 vA = *(const uint2*)(ys + (size_t)sA * 768 + 256 + cb);
            uint2 vB = *(const uint2*)(ys + (size_t)sB * 768 + 256 + cb);
            uint2 vC = *(const uint2*)(ys + (size_t)sC * 768 + 256 + cb);
            uint2 vD = *(const uint2*)(ys + (size_t)sD * 768 + 256 + cb);
            a0 += bflo(vA.x) + bflo(vB.x) + bflo(vC.x) + bflo(vD.x);
            a1 += bfhi(vA.x) + bfhi(vB.x) + bfhi(vC.x) + bfhi(vD.x);
            a2 += bflo(vA.y) + bflo(vB.y) + bflo(vC.y) + bflo(vD.y);
            a3 += bfhi(vA.y) + bfhi(vB.y) + bfhi(vC.y) + bfhi(vD.y);
        }
        for (; e < s1; ++e) {
            int s = col[e];
            uint2 v = *(const uint2*)(ys + (size_t)s * 768 + 256 + cb);
            a0 += bflo(v.x); a1 += bfhi(v.x); a2 += bflo(v.y); a3 += bfhi(v.y);
        }
        float inv = 1.f / (float)max(s1 - s0, 1);
        float m0 = a0 * inv, m1 = a1 * inv, m2 = a2 * inv, m3 = a3 * inv;
        a0 = a1 = a2 = a3 = 0.f;
        int t0 = rowptr[NS + d], t1 = rowptr[NS + d + 1];
        for (e = t0; e < t1; ++e) {
            int s = col[e];
            uint2 v = *(const uint2*)(yd + (size_t)s * 512 + cb);
            a0 += bflo(v.x); a1 += bfhi(v.x); a2 += bflo(v.y); a3 += bfhi(v.y);
        }
        inv = 1.f / (float)max(t1 - t0, 1);
        uint2 lv = *(const uint2*)(ys + (size_t)d * 768 + 512 + cb);
        float h0 = fmaxf(m0 + a0 * inv + bflo(lv.x) + b0, 0.f);
        float h1 = fmaxf(m1 + a1 * inv + bfhi(lv.x) + b1, 0.f);
        float h2 = fmaxf(m2 + a2 * inv + bflo(lv.y) + b2, 0.f);
        float h3 = fmaxf(m3 + a3 * inv + bfhi(lv.y) + b3, 0.f);
        uint2 o;
        o.x = (unsigned)f2bf(h0) | ((unsigned)f2bf(h1) << 16);
        o.y = (unsigned)f2bf(h2) | ((unsigned)f2bf(h3) << 16);
        *(uint2*)(h1s + (size_t)d * 256 + cb) = o;
    } else if (d < NS + ND) {
        // ---- doc dst: mean_sd(ys[:,0:256]) + yd[dd,256:512] ----
        int dd = d - NS;
        float a0 = 0, a1 = 0, a2 = 0, a3 = 0;
        int s0 = rowptr[2 * NS + dd], s1 = rowptr[2 * NS + dd + 1];
        int e = s0;
        for (; e + 4 <= s1; e += 4) {
            int sA = col[e], sB = col[e + 1], sC = col[e + 2], sD = col[e + 3];
            uint2 vA = *(const uint2*)(ys + (size_t)sA * 768 + cb);
            uint2 vB = *(const uint2*)(ys + (size_t)sB * 768 + cb);
            uint2 vC = *(const uint2*)(ys + (size_t)sC * 768 + cb);
            uint2 vD = *(const uint2*)(ys + (size_t)sD * 768 + cb);
            a0 += bflo(vA.x) + bflo(vB.x) + bflo(vC.x) + bflo(vD.x);
            a1 += bfhi(vA.x) + bfhi(vB.x) + bfhi(vC.x) + bfhi(vD.x);
            a2 += bflo(vA.y) + bflo(vB.y) + bflo(vC.y) + bflo(vD.y);
            a3 += bfhi(vA.y) + bfhi(vB.y) + bfhi(vC.y) + bfhi(vD.y);
        }
        for (; e < s1; ++e) {
            int s = col[e];
            uint2 v = *(const uint2*)(ys + (size_t)s * 768 + cb);
            a0 += bflo(v.x); a1 += bfhi(v.x); a2 += bflo(v.y); a3 += bfhi(v.y);
        }
        float inv = 1.f / (float)max(s1 - s0, 1);
        uint2 lv = *(const uint2*)(yd + (size_t)dd * 512 + 256 + cb);
        float h0 = fmaxf(a0 * inv + bflo(lv.x) + b0, 0.f);
        float h1 = fmaxf(a1 * inv + bfhi(lv.x) + b1, 0.f);
        float h2 = fmaxf(a2 * inv + bflo(lv.y) + b2, 0.f);
        float h3 = fmaxf(a3 * inv + bfhi(lv.y) + b3, 0.f);
        uint2 o;
        o.x = (unsigned)f2bf(h0) | ((unsigned)f2bf(h1) << 16);
        o.y = (unsigned)f2bf(h2) | ((unsigned)f2bf(h3) << 16);
        *(uint2*)(h1d + (size_t)dd * 256 + cb) = o;
    }
}

__global__ __launch_bounds__(256) void gather_l2(
    const ushort* __restrict__ ys, const ushort* __restrict__ yd,
    const int* __restrict__ rowptr, const int* __restrict__ col,
    const float* __restrict__ bias, const float* __restrict__ w,
    const int* __restrict__ gid_s, const int* __restrict__ gid_d,
    float* __restrict__ out, int NS, int ND, int G) {
    __shared__ float part[4][32];
    const int tid = threadIdx.x;
    const int lane = tid & 63, wv = tid >> 6;
    const int cb = lane * 2;
    const float w0 = w[cb], w1 = w[cb + 1];
    const float b0 = bias[cb], b1 = bias[cb + 1];
    float racc = 0.f;
    const int nw = gridDim.x * 4;
    for (int d = blockIdx.x * 4 + wv; d < NS + ND; d += nw) {
        float h0, h1; int g;
        if (d < NS) {
            float a0 = 0.f, a1 = 0.f;
            int s0 = rowptr[d], s1 = rowptr[d + 1];
            int e = s0;
            for (; e + 4 <= s1; e += 4) {
                int sA = col[e], sB = col[e + 1], sC = col[e + 2], sD = col[e + 3];
                unsigned vA = *(const unsigned*)(ys + (size_t)sA * 384 + 128 + cb);
                unsigned vB = *(const unsigned*)(ys + (size_t)sB * 384 + 128 + cb);
                unsigned vC = *(const unsigned*)(ys + (size_t)sC * 384 + 128 + cb);
                unsigned vD = *(const unsigned*)(ys + (size_t)sD * 384 + 128 + cb);
                a0 += bflo(vA) + bflo(vB) + bflo(vC) + bflo(vD);
                a1 += bfhi(vA) + bfhi(vB) + bfhi(vC) + bfhi(vD);
            }
            for (; e < s1; ++e) {
                int s = col[e];
                unsigned v = *(const unsigned*)(ys + (size_t)s * 384 + 128 + cb);
                a0 += bflo(v); a1 += bfhi(v);
            }
            float inv = 1.f / (float)max(s1 - s0, 1);
            float m0 = a0 * inv, m1 = a1 * inv;
            a0 = 0.f; a1 = 0.f;
            int t0 = rowptr[NS + d], t1 = rowptr[NS + d + 1];
            for (e = t0; e < t1; ++e) {
                int s = col[e];
                unsigned v = *(const unsigned*)(yd + (size_t)s * 256 + cb);
                a0 += bflo(v); a1 += bfhi(v);
            }
            inv = 1.f / (float)max(t1 - t0, 1);
            unsigned lv = *(const unsigned*)(ys + (size_t)d * 384 + 256 + cb);
            h0 = fmaxf(m0 + a0 * inv + bflo(lv) + b0, 0.f);
            h1 = fmaxf(m1 + a1 * inv + bfhi(lv) + b1, 0.f);
            g = gid_s[d];
        } else {
            int dd = d - NS;
            float a0 = 0.f, a1 = 0.f;
            int s0 = rowptr[2 * NS + dd], s1 = rowptr[2 * NS + dd + 1];
            int e = s0;
            for (; e + 4 <= s1; e += 4) {
                int sA = col[e], sB = col[e + 1], sC = col[e + 2], sD = col[e + 3];
                unsigned vA = *(const unsigned*)(ys + (size_t)sA * 384 + cb);
                unsigned vB = *(const unsigned*)(ys + (size_t)sB * 384 + cb);
                unsigned vC = *(const unsigned*)(ys + (size_t)sC * 384 + cb);
                unsigned vD = *(const unsigned*)(ys + (size_t)sD * 384 + cb);
                a0 += bflo(vA) + bflo(vB) + bflo(vC) + bflo(vD);
                a1 += bfhi(vA) + bfhi(vB) + bfhi(vC) + bfhi(vD);
            }
            for (; e < s1; ++e) {
                int s = col[e];
                unsigned v = *(const unsigned*)(ys + (size_t)s * 384 + cb);
                a0 += bflo(v); a1 += bfhi(v);
            }
            float inv = 1.f / (float)max(s1 - s0, 1);
            unsigned lv = *(const unsigned*)(yd + (size_t)dd * 256 + 128 + cb);
            h0 = fmaxf(a0 * inv + bflo(lv) + b0, 0.f);
            h1 = fmaxf(a1 * inv + bfhi(lv) + b1, 0.f);
            g = gid_d[dd];
        }
        float sc = h0 * w0 + h1 * w1;
#pragma unroll
        for (int o = 32; o; o >>= 1) sc += __shfl_down(sc, o);
        sc = __shfl(sc, 0);
        if (lane == g) racc += sc;
    }
    if (lane < 32) part[wv][lane] = racc;
    __syncthreads();
    if (tid < G) atomicAdd(&out[tid], part[0][tid] + part[1][tid] + part[2][tid] + part[3][tid]);
}

__global__ void init_out(float* __restrict__ out, const float* __restrict__ b, int G) {
    int i = threadIdx.x;
    if (i < G) out[i] = b[0];
}

// ---------------- launch ----------------

extern "C" void kernel_launch(void* const* d_in, const int* in_sizes, int n_in,
                              void* d_out, int out_size, void* d_ws, size_t ws_size,
                              hipStream_t stream) {
    const float* x_sent = (const float*)d_in[0];
    const float* x_doc  = (const float*)d_in[1];
    const float* coeff1 = (const float*)d_in[2];
    const float* basis1 = (const float*)d_in[3];
    const float* loopw1 = (const float*)d_in[4];
    const float* bias1  = (const float*)d_in[5];
    const float* coeff2 = (const float*)d_in[6];
    const float* basis2 = (const float*)d_in[7];
    const float* loopw2 = (const float*)d_in[8];
    const float* bias2  = (const float*)d_in[9];
    const float* wscore = (const float*)d_in[10];
    const float* bscore = (const float*)d_in[11];
    const int* src_ss = (const int*)d_in[12];
    const int* dst_ss = (const int*)d_in[13];
    const int* src_sd = (const int*)d_in[14];
    const int* dst_sd = (const int*)d_in[15];
    const int* src_ds = (const int*)d_in[16];
    const int* dst_ds = (const int*)d_in[17];
    const int* gid_sent = (const int*)d_in[18];
    const int* gid_doc  = (const int*)d_in[19];

    const int DIN = 768, DH = 256, DOo = 128;
    const int NS = in_sizes[0] / DIN;     // 100000
    const int ND = in_sizes[1] / DIN;     // 10000
    const int E_SS = in_sizes[12], E_SD = in_sizes[14], E_DS = in_sizes[16];
    const int NTOT = NS + NS + ND;
    const int ETOT = E_SS + E_DS + E_SD;
    const int G = out_size;
    float* out = (float*)d_out;

    char* base = (char*)d_ws;
    size_t off = 0;
    auto alloc = [&](size_t bytes) -> char* {
        char* p = base + off;
        off = (off + bytes + 255) & ~(size_t)255;
        return p;
    };
    ushort* B1sT = (ushort*)alloc((size_t)768 * 768 * 2);
    ushort* B1dT = (ushort*)alloc((size_t)512 * 768 * 2);
    ushort* B2sT = (ushort*)alloc((size_t)384 * 256 * 2);
    ushort* B2dT = (ushort*)alloc((size_t)256 * 256 * 2);
    ushort* ys1 = (ushort*)alloc((size_t)NS * 768 * 2);
    ushort* yd1 = (ushort*)alloc((size_t)ND * 512 * 2);
    ushort* h1s = (ushort*)alloc((size_t)NS * 256 * 2);
    ushort* h1d = (ushort*)alloc((size_t)ND * 256 * 2);
    ushort* ys2 = (ushort*)alloc((size_t)NS * 384 * 2);
    ushort* yd2 = (ushort*)alloc((size_t)ND * 256 * 2);
    int* deg  = (int*)alloc((size_t)2 * NTOT * 4);
    int* fill = deg + NTOT;
    int* rowptr = (int*)alloc((size_t)(NTOT + 1) * 4);
    int* bsum = (int*)alloc(256 * 4);
    int* colall = (int*)alloc((size_t)ETOT * 4);

    // ---- weights (1 kernel per layer, 5 sections each) ----
    long long t1 = (long long)768 * DH, t2 = (long long)256 * DOo;
    fill_w5<<<dim3((unsigned)CDIV(t1, 256), 5), 256, 0, stream>>>(B1sT, B1dT, basis1, loopw1, coeff1, 768, DH, t1);
    fill_w5<<<dim3((unsigned)CDIV(t2, 256), 5), 256, 0, stream>>>(B2sT, B2dT, basis2, loopw2, coeff2, 256, DOo, t2);

    // ---- CSR build ----
    zero_f4<<<(int)CDIV(2 * NTOT / 4, 256), 256, 0, stream>>>((float4*)deg, 2 * NTOT / 4);
    accum_deg_all<<<CDIV(ETOT, 256), 256, 0, stream>>>(dst_ss, dst_ds, dst_sd, E_SS, E_DS, E_SD, NS, deg);
    int nb = CDIV(NTOT, 1024);
    scan_p1<<<nb, 256, 0, stream>>>(deg, NTOT, bsum);
    scan_p2<<<1, 256, 0, stream>>>(bsum, nb, rowptr, NTOT, ETOT);
    scan_p3<<<nb, 256, 0, stream>>>(deg, NTOT, bsum, rowptr);
    fill_csr_all<<<CDIV(ETOT, 256), 256, 0, stream>>>(src_ss, dst_ss, src_ds, dst_ds, src_sd, dst_sd,
                                                      E_SS, E_DS, E_SD, NS, rowptr, fill, colall);

    // ---- layer 1 GEMMs: A f32 direct-frag, XCD-swizzled 1-D grid ----
    {
        int mb = CDIV(NS, 128), mb0 = mb / 2;
        int M0 = mb0 * 128;
        gemm_any<true><<<6 * mb0, 256, 0, stream>>>(x_sent, B1sT, ys1, M0, 768, 768, 6);
        gemm_any<true><<<6 * (mb - mb0), 256, 0, stream>>>(
            x_sent + (size_t)M0 * 768, B1sT, ys1 + (size_t)M0 * 768, NS - M0, 768, 768, 6);
    }
    gemm_any<true><<<4 * CDIV(ND, 128), 256, 0, stream>>>(x_doc, B1dT, yd1, ND, 768, 512, 4);

    gather_l1<<<CDIV(NS + ND, 4), 256, 0, stream>>>(ys1, yd1, rowptr, colall, bias1, h1s, h1d, NS, ND);

    // ---- layer 2 (A bf16 direct-frag, linear h1) ----
    gemm_any<false><<<3 * CDIV(NS, 128), 256, 0, stream>>>(h1s, B2sT, ys2, NS, 256, 384, 3);
    gemm_any<false><<<2 * CDIV(ND, 128), 256, 0, stream>>>(h1d, B2dT, yd2, ND, 256, 256, 2);

    init_out<<<1, 64, 0, stream>>>(out, bscore, G);
    gather_l2<<<1100, 256, 0, stream>>>(ys2, yd2, rowptr, colall, bias2, wscore,
                                        gid_sent, gid_doc, out, NS, ND, G);
}

// Round 7
// 936.893 us; speedup vs baseline: 1.3806x; 1.3806x over previous
//
#include <hip/hip_runtime.h>

#define CDIV(a,b) (((a)+(b)-1)/(b))

typedef __attribute__((ext_vector_type(8))) short bf16x8;
typedef __attribute__((ext_vector_type(4))) float floatx4;

__device__ __forceinline__ ushort f2bf(float x) {
    unsigned u = __float_as_uint(x);
    return (ushort)((u + 0x7fffu + ((u >> 16) & 1u)) >> 16);   // RNE
}
__device__ __forceinline__ unsigned cvtpk(float lo, float hi) {
    unsigned r;
    asm("v_cvt_pk_bf16_f32 %0, %1, %2" : "=v"(r) : "v"(lo), "v"(hi));
    return r;   // RNE pack: low16 = bf16(lo), high16 = bf16(hi)
}
__device__ __forceinline__ float bflo(unsigned v) { return __uint_as_float(v << 16); }
__device__ __forceinline__ float bfhi(unsigned v) { return __uint_as_float(v & 0xffff0000u); }

__device__ __forceinline__ void load_lds16(const ushort* g, ushort* l) {
    __builtin_amdgcn_global_load_lds(
        (const __attribute__((address_space(1))) void*)g,
        (__attribute__((address_space(3))) void*)l, 16, 0, 0);
}

// LDS tile layout: [128 rows][64 bf16], XOR-swizzled within each 64-col block:
//   LDS[row][c] holds element (row, kb*64 + (c ^ ((row&7)<<3)))  [c in ushorts]
// Producers of global bf16 operand panels (fill_w5, gather_l1) pre-permute the
// 64-col blocks the same way, so linear global_load_lds staging lands swizzled
// and ds_read applies the same XOR -> conflict-free fragment reads (T2, G4).

// ---------------- utility kernels ----------------

__global__ void zero_f4(float4* __restrict__ p, long long n4) {
    long long i = blockIdx.x * 256LL + threadIdx.x;
    if (i < n4) p[i] = make_float4(0.f, 0.f, 0.f, 0.f);
}

// One layer's 5 weight blocks, transposed bf16, K-swizzled. sections (blockIdx.y):
// 0: BsT col0=0   rel0 | 1: BsT col0=N rel2 | 2: BsT col0=2N loop | 3: BdT col0=0 rel1 | 4: BdT col0=N loop
__global__ void fill_w5(ushort* __restrict__ BsT, ushort* __restrict__ BdT,
                        const float* __restrict__ basis, const float* __restrict__ loopw,
                        const float* __restrict__ coeff, int K, int N, long long KN) {
    long long i = blockIdx.x * 256LL + threadIdx.x;
    if (i >= KN) return;
    int k = (int)(i % K), n = (int)(i / K);
    int sec = blockIdx.y;
    float val;
    if (sec == 2 || sec == 4) {
        val = loopw[(size_t)k * N + n];
    } else {
        int r = (sec == 0) ? 0 : (sec == 1) ? 2 : 1;
        val = coeff[2 * r] * basis[(size_t)k * N + n] + coeff[2 * r + 1] * basis[KN + (size_t)k * N + n];
    }
    ushort* dst = (sec < 3) ? BsT : BdT;
    int col0 = (sec == 0) ? 0 : (sec == 1) ? N : (sec == 2) ? 2 * N : (sec == 3) ? 0 : N;
    int nn = col0 + n;
    dst[(size_t)nn * K + (k & ~63) + ((k & 63) ^ ((nn & 7) << 3))] = f2bf(val);
}

// ---------------- CSR build ----------------

__global__ void accum_deg_all(const int* __restrict__ dss, const int* __restrict__ dds,
                              const int* __restrict__ dsd, int nss, int nds, int nsd,
                              int NS, int* __restrict__ deg) {
    int i = blockIdx.x * 256 + threadIdx.x;
    if (i < nss) atomicAdd(&deg[dss[i]], 1);
    else if (i < nss + nds) atomicAdd(&deg[NS + dds[i - nss]], 1);
    else if (i < nss + nds + nsd) atomicAdd(&deg[2 * NS + dsd[i - nss - nds]], 1);
}

__global__ void scan_p1(const int* __restrict__ deg, int n, int* __restrict__ bsum) {
    __shared__ int sd[256];
    int blk = blockIdx.x, tid = threadIdx.x;
    int i0 = blk * 1024 + tid * 4;
    int s = 0;
#pragma unroll
    for (int j = 0; j < 4; ++j) if (i0 + j < n) s += deg[i0 + j];
    sd[tid] = s; __syncthreads();
    for (int o = 128; o; o >>= 1) {
        if (tid < o) sd[tid] += sd[tid + o];
        __syncthreads();
    }
    if (tid == 0) bsum[blk] = sd[0];
}

__global__ void scan_p2(int* __restrict__ bsum, int nb, int* __restrict__ rowptr, int ntot, int etot) {
    __shared__ int sd[256];
    int tid = threadIdx.x;
    int v = (tid < nb) ? bsum[tid] : 0;
    sd[tid] = v; __syncthreads();
    for (int o = 1; o < 256; o <<= 1) {
        int t = (tid >= o) ? sd[tid - o] : 0;
        __syncthreads();
        sd[tid] += t;
        __syncthreads();
    }
    if (tid < nb) bsum[tid] = sd[tid] - v;
    if (tid == 0) rowptr[ntot] = etot;
}

__global__ void scan_p3(const int* __restrict__ deg, int n, const int* __restrict__ bsum,
                        int* __restrict__ rowptr) {
    __shared__ int sd[256];
    int blk = blockIdx.x, tid = threadIdx.x;
    int i0 = blk * 1024 + tid * 4;
    int v[4]; int s = 0;
#pragma unroll
    for (int j = 0; j < 4; ++j) { v[j] = (i0 + j < n) ? deg[i0 + j] : 0; s += v[j]; }
    sd[tid] = s; __syncthreads();
    for (int o = 1; o < 256; o <<= 1) {
        int t = (tid >= o) ? sd[tid - o] : 0;
        __syncthreads();
        sd[tid] += t;
        __syncthreads();
    }
    int excl = bsum[blk] + sd[tid] - s;
#pragma unroll
    for (int j = 0; j < 4; ++j) {
        if (i0 + j < n) rowptr[i0 + j] = excl;
        excl += v[j];
    }
}

__global__ void fill_csr_all(const int* __restrict__ sss, const int* __restrict__ dss,
                             const int* __restrict__ sds, const int* __restrict__ dds,
                             const int* __restrict__ ssd, const int* __restrict__ dsd,
                             int nss, int nds, int nsd, int NS,
                             const int* __restrict__ rowptr, int* __restrict__ fill,
                             int* __restrict__ col) {
    int i = blockIdx.x * 256 + threadIdx.x;
    int d, s;
    if (i < nss) { d = dss[i]; s = sss[i]; }
    else if (i < nss + nds) { int j = i - nss; d = NS + dds[j]; s = sds[j]; }
    else if (i < nss + nds + nsd) { int j = i - nss - nds; d = 2 * NS + dsd[j]; s = ssd[j]; }
    else return;
    int p = rowptr[d] + atomicAdd(&fill[d], 1);
    col[p] = s;
}

// ---------------- MFMA GEMM: C[M,N] bf16 = A[M,K] @ Bt[N,K]^T ----------------
// AF32=true : A is f32, converted to bf16 in-staging (fused cvt, v_cvt_pk_bf16_f32),
//             swizzled ds_write
// AF32=false: A is bf16 pre-swizzled in global, staged via global_load_lds
// B always bf16 pre-swizzled in global (fill_w5), staged via global_load_lds.
// XCD-bijective 1-D grid swizzle (m204) for A-panel L2 reuse.
// BK=64: 12 barriers for K=768, 32 MFMA per K-step, conflict-free LDS reads.
template<bool AF32>
__global__ __launch_bounds__(256) void gemm_any(
    const void* __restrict__ Araw, const ushort* __restrict__ Bt, ushort* __restrict__ C,
    int M, int K, int N, int BNX) {
    const int nwg = gridDim.x;
    const int orig = blockIdx.x;
    const int q = nwg >> 3, r = nwg & 7;
    const int xcd = orig & 7, idx = orig >> 3;
    const int wg = (xcd < r ? xcd * (q + 1) : r * (q + 1) + (xcd - r) * q) + idx;
    const int bn = (wg % BNX) * 128;
    const long long bm = (long long)(wg / BNX) * 128LL;

    __shared__ ushort As[128 * 64];
    __shared__ ushort Bs[128 * 64];
    const int tid = threadIdx.x;
    const int lane = tid & 63, wave = tid >> 6;
    const int mo = (wave & 1) * 64, no = (wave >> 1) * 64;
    const int l15 = lane & 15, quad = lane >> 4;
    const int srow = wave * 8 + (lane >> 3);   // staging row within 32-row group
    const int bch = (lane & 7) * 8;            // staging chunk (ushorts) within 64
    floatx4 acc[4][4] = {};

    for (int k0 = 0; k0 < K; k0 += 64) {
        // ---- B stage: 4 x global_load_lds (async), linear dest, pre-swizzled src ----
#pragma unroll
        for (int t = 0; t < 4; ++t) {
            int row = t * 32 + srow;
            load_lds16(Bt + (size_t)(bn + row) * K + k0 + bch,
                       Bs + (t * 32 + wave * 8) * 64);
        }
        if (AF32) {
            // ---- A f32 -> regs (8x dwordx4 in flight) -> cvt_pk -> swizzled ds_write ----
            float4 pre[4][2];
#pragma unroll
            for (int j = 0; j < 4; ++j) {
                int s = j * 256 + tid;
                int arow = s >> 3, ach = s & 7;
                long long ar = bm + arow; if (ar >= M) ar = M - 1;
                const float* ap = (const float*)Araw + ar * (size_t)K + k0 + ach * 8;
                pre[j][0] = *(const float4*)ap;
                pre[j][1] = *(const float4*)(ap + 4);
            }
#pragma unroll
            for (int j = 0; j < 4; ++j) {
                int s = j * 256 + tid;
                int arow = s >> 3, ach = s & 7;
                uint4 o;
                o.x = cvtpk(pre[j][0].x, pre[j][0].y);
                o.y = cvtpk(pre[j][0].z, pre[j][0].w);
                o.z = cvtpk(pre[j][1].x, pre[j][1].y);
                o.w = cvtpk(pre[j][1].z, pre[j][1].w);
                *(uint4*)(As + arow * 64 + ((ach * 8) ^ ((arow & 7) << 3))) = o;
            }
        } else {
            // ---- A bf16 (pre-swizzled global): 4 x global_load_lds ----
#pragma unroll
            for (int t = 0; t < 4; ++t) {
                int row = t * 32 + srow;
                long long ar = bm + row; if (ar >= M) ar = M - 1;
                load_lds16((const ushort*)Araw + ar * (size_t)K + k0 + bch,
                           As + (t * 32 + wave * 8) * 64);
            }
        }
        __syncthreads();
        // ---- fragment reads (XOR-swizzled, conflict-free) + 32 MFMA ----
        bf16x8 af[2][4], bfr[2][4];
#pragma unroll
        for (int h = 0; h < 2; ++h) {
#pragma unroll
            for (int mt = 0; mt < 4; ++mt) {
                int row = mo + mt * 16 + l15;
                af[h][mt] = *(const bf16x8*)(As + row * 64 + ((h * 32 + quad * 8) ^ ((row & 7) << 3)));
            }
#pragma unroll
            for (int nt = 0; nt < 4; ++nt) {
                int row = no + nt * 16 + l15;
                bfr[h][nt] = *(const bf16x8*)(Bs + row * 64 + ((h * 32 + quad * 8) ^ ((row & 7) << 3)));
            }
        }
#pragma unroll
        for (int h = 0; h < 2; ++h)
#pragma unroll
            for (int mt = 0; mt < 4; ++mt)
#pragma unroll
                for (int nt = 0; nt < 4; ++nt)
                    acc[mt][nt] = __builtin_amdgcn_mfma_f32_16x16x32_bf16(af[h][mt], bfr[h][nt], acc[mt][nt], 0, 0, 0);
        __syncthreads();
    }
#pragma unroll
    for (int mt = 0; mt < 4; ++mt)
#pragma unroll
        for (int i = 0; i < 4; ++i) {
            long long row = bm + mo + mt * 16 + quad * 4 + i;
            if (row < M) {
#pragma unroll
                for (int nt = 0; nt < 4; ++nt)
                    C[row * (size_t)N + bn + no + nt * 16 + l15] = f2bf(acc[mt][nt][i]);
            }
        }
}

// ---------------- fused gather kernels (sent + doc merged) ----------------
// one wave per dst node; edge loops unrolled x4 for memory-level parallelism
// h1s/h1d outputs are written in the K-swizzled layout consumed by layer-2 GEMM A.

__global__ __launch_bounds__(256) void gather_l1(
    const ushort* __restrict__ ys, const ushort* __restrict__ yd,
    const int* __restrict__ rowptr, const int* __restrict__ col,
    const float* __restrict__ bias, ushort* __restrict__ h1s, ushort* __restrict__ h1d,
    int NS, int ND) {
    int d = blockIdx.x * 4 + (threadIdx.x >> 6);
    int lane = threadIdx.x & 63;
    int cb = lane * 4;
    float b0 = bias[cb], b1 = bias[cb + 1], b2 = bias[cb + 2], b3 = bias[cb + 3];
    if (d < NS) {
        // ---- sent dst: mean_ss(ys[:,256:512]) + mean_ds(yd[:,0:256]) + ys[d,512:768] ----
        float a0 = 0, a1 = 0, a2 = 0, a3 = 0;
        int s0 = rowptr[d], s1 = rowptr[d + 1];
        int e = s0;
        for (; e + 4 <= s1; e += 4) {
            int sA = col[e], sB = col[e + 1], sC = col[e + 2], sD = col[e + 3];
            uint2 vA = *(const uint2*)(ys + (size_t)sA * 768 + 256 + cb);
            uint2 vB = *(const uint2*)(ys + (size_t)sB * 768 + 256 + cb);
            uint2 vC = *(const uint2*)(ys + (size_t)sC * 768 + 256 + cb);
            uint2 vD = *(const uint2*)(ys + (size_t)sD * 768 + 256 + cb);
            a0 += bflo(vA.x) + bflo(vB.x) + bflo(vC.x) + bflo(vD.x);
            a1 += bfhi(vA.x) + bfhi(vB.x) + bfhi(vC.x) + bfhi(vD.x);
            a2 += bflo(vA.y) + bflo(vB.y) + bflo(vC.y) + bflo(vD.y);
            a3 += bfhi(vA.y) + bfhi(vB.y) + bfhi(vC.y) + bfhi(vD.y);
        }
        for (; e < s1; ++e) {
            int s = col[e];
            uint2 v = *(const uint2*)(ys + (size_t)s * 768 + 256 + cb);
            a0 += bflo(v.x); a1 += bfhi(v.x); a2 += bflo(v.y); a3 += bfhi(v.y);
        }
        float inv = 1.f / (float)max(s1 - s0, 1);
        float m0 = a0 * inv, m1 = a1 * inv, m2 = a2 * inv, m3 = a3 * inv;
        a0 = a1 = a2 = a3 = 0.f;
        int t0 = rowptr[NS + d], t1 = rowptr[NS + d + 1];
        for (e = t0; e < t1; ++e) {
            int s = col[e];
            uint2 v = *(const uint2*)(yd + (size_t)s * 512 + cb);
            a0 += bflo(v.x); a1 += bfhi(v.x); a2 += bflo(v.y); a3 += bfhi(v.y);
        }
        inv = 1.f / (float)max(t1 - t0, 1);
        uint2 lv = *(const uint2*)(ys + (size_t)d * 768 + 512 + cb);
        float h0 = fmaxf(m0 + a0 * inv + bflo(lv.x) + b0, 0.f);
        float h1 = fmaxf(m1 + a1 * inv + bfhi(lv.x) + b1, 0.f);
        float h2 = fmaxf(m2 + a2 * inv + bflo(lv.y) + b2, 0.f);
        float h3 = fmaxf(m3 + a3 * inv + bfhi(lv.y) + b3, 0.f);
        uint2 o;
        o.x = cvtpk(h0, h1);
        o.y = cvtpk(h2, h3);
        int pos = (cb & ~63) + ((cb & 63) ^ ((d & 7) << 3));
        *(uint2*)(h1s + (size_t)d * 256 + pos) = o;
    } else if (d < NS + ND) {
        // ---- doc dst: mean_sd(ys[:,0:256]) + yd[dd,256:512] ----
        int dd = d - NS;
        float a0 = 0, a1 = 0, a2 = 0, a3 = 0;
        int s0 = rowptr[2 * NS + dd], s1 = rowptr[2 * NS + dd + 1];
        int e = s0;
        for (; e + 4 <= s1; e += 4) {
            int sA = col[e], sB = col[e + 1], sC = col[e + 2], sD = col[e + 3];
            uint2 vA = *(const uint2*)(ys + (size_t)sA * 768 + cb);
            uint2 vB = *(const uint2*)(ys + (size_t)sB * 768 + cb);
            uint2 vC = *(const uint2*)(ys + (size_t)sC * 768 + cb);
            uint2 vD = *(const uint2*)(ys + (size_t)sD * 768 + cb);
            a0 += bflo(vA.x) + bflo(vB.x) + bflo(vC.x) + bflo(vD.x);
            a1 += bfhi(vA.x) + bfhi(vB.x) + bfhi(vC.x) + bfhi(vD.x);
            a2 += bflo(vA.y) + bflo(vB.y) + bflo(vC.y) + bflo(vD.y);
            a3 += bfhi(vA.y) + bfhi(vB.y) + bfhi(vC.y) + bfhi(vD.y);
        }
        for (; e < s1; ++e) {
            int s = col[e];
            uint2 v = *(const uint2*)(ys + (size_t)s * 768 + cb);
            a0 += bflo(v.x); a1 += bfhi(v.x); a2 += bflo(v.y); a3 += bfhi(v.y);
        }
        float inv = 1.f / (float)max(s1 - s0, 1);
        uint2 lv = *(const uint2*)(yd + (size_t)dd * 512 + 256 + cb);
        float h0 = fmaxf(a0 * inv + bflo(lv.x) + b0, 0.f);
        float h1 = fmaxf(a1 * inv + bfhi(lv.x) + b1, 0.f);
        float h2 = fmaxf(a2 * inv + bflo(lv.y) + b2, 0.f);
        float h3 = fmaxf(a3 * inv + bfhi(lv.y) + b3, 0.f);
        uint2 o;
        o.x = cvtpk(h0, h1);
        o.y = cvtpk(h2, h3);
        int pos = (cb & ~63) + ((cb & 63) ^ ((dd & 7) << 3));
        *(uint2*)(h1d + (size_t)dd * 256 + pos) = o;
    }
}

__global__ __launch_bounds__(256) void gather_l2(
    const ushort* __restrict__ ys, const ushort* __restrict__ yd,
    const int* __restrict__ rowptr, const int* __restrict__ col,
    const float* __restrict__ bias, const float* __restrict__ w,
    const int* __restrict__ gid_s, const int* __restrict__ gid_d,
    float* __restrict__ out, int NS, int ND, int G) {
    __shared__ float part[4][32];
    const int tid = threadIdx.x;
    const int lane = tid & 63, wv = tid >> 6;
    const int cb = lane * 2;
    const float w0 = w[cb], w1 = w[cb + 1];
    const float b0 = bias[cb], b1 = bias[cb + 1];
    float racc = 0.f;
    const int nw = gridDim.x * 4;
    for (int d = blockIdx.x * 4 + wv; d < NS + ND; d += nw) {
        float h0, h1; int g;
        if (d < NS) {
            float a0 = 0.f, a1 = 0.f;
            int s0 = rowptr[d], s1 = rowptr[d + 1];
            int e = s0;
            for (; e + 4 <= s1; e += 4) {
                int sA = col[e], sB = col[e + 1], sC = col[e + 2], sD = col[e + 3];
                unsigned vA = *(const unsigned*)(ys + (size_t)sA * 384 + 128 + cb);
                unsigned vB = *(const unsigned*)(ys + (size_t)sB * 384 + 128 + cb);
                unsigned vC = *(const unsigned*)(ys + (size_t)sC * 384 + 128 + cb);
                unsigned vD = *(const unsigned*)(ys + (size_t)sD * 384 + 128 + cb);
                a0 += bflo(vA) + bflo(vB) + bflo(vC) + bflo(vD);
                a1 += bfhi(vA) + bfhi(vB) + bfhi(vC) + bfhi(vD);
            }
            for (; e < s1; ++e) {
                int s = col[e];
                unsigned v = *(const unsigned*)(ys + (size_t)s * 384 + 128 + cb);
                a0 += bflo(v); a1 += bfhi(v);
            }
            float inv = 1.f / (float)max(s1 - s0, 1);
            float m0 = a0 * inv, m1 = a1 * inv;
            a0 = 0.f; a1 = 0.f;
            int t0 = rowptr[NS + d], t1 = rowptr[NS + d + 1];
            for (e = t0; e < t1; ++e) {
                int s = col[e];
                unsigned v = *(const unsigned*)(yd + (size_t)s * 256 + cb);
                a0 += bflo(v); a1 += bfhi(v);
            }
            inv = 1.f / (float)max(t1 - t0, 1);
            unsigned lv = *(const unsigned*)(ys + (size_t)d * 384 + 256 + cb);
            h0 = fmaxf(m0 + a0 * inv + bflo(lv) + b0, 0.f);
            h1 = fmaxf(m1 + a1 * inv + bfhi(lv) + b1, 0.f);
            g = gid_s[d];
        } else {
            int dd = d - NS;
            float a0 = 0.f, a1 = 0.f;
            int s0 = rowptr[2 * NS + dd], s1 = rowptr[2 * NS + dd + 1];
            int e = s0;
            for (; e + 4 <= s1; e += 4) {
                int sA = col[e], sB = col[e + 1], sC = col[e + 2], sD = col[e + 3];
                unsigned vA = *(const unsigned*)(ys + (size_t)sA * 384 + cb);
                unsigned vB = *(const unsigned*)(ys + (size_t)sB * 384 + cb);
                unsigned vC = *(const unsigned*)(ys + (size_t)sC * 384 + cb);
                unsigned vD = *(const unsigned*)(ys + (size_t)sD * 384 + cb);
                a0 += bflo(vA) + bflo(vB) + bflo(vC) + bflo(vD);
                a1 += bfhi(vA) + bfhi(vB) + bfhi(vC) + bfhi(vD);
            }
            for (; e < s1; ++e) {
                int s = col[e];
                unsigned v = *(const unsigned*)(ys + (size_t)s * 384 + cb);
                a0 += bflo(v); a1 += bfhi(v);
            }
            float inv = 1.f / (float)max(s1 - s0, 1);
            unsigned lv = *(const unsigned*)(yd + (size_t)dd * 256 + 128 + cb);
            h0 = fmaxf(a0 * inv + bflo(lv) + b0, 0.f);
            h1 = fmaxf(a1 * inv + bfhi(lv) + b1, 0.f);
            g = gid_d[dd];
        }
        float sc = h0 * w0 + h1 * w1;
#pragma unroll
        for (int o = 32; o; o >>= 1) sc += __shfl_down(sc, o);
        sc = __shfl(sc, 0);
        if (lane == g) racc += sc;
    }
    if (lane < 32) part[wv][lane] = racc;
    __syncthreads();
    if (tid < G) atomicAdd(&out[tid], part[0][tid] + part[1][tid] + part[2][tid] + part[3][tid]);
}

__global__ void init_out(float* __restrict__ out, const float* __restrict__ b, int G) {
    int i = threadIdx.x;
    if (i < G) out[i] = b[0];
}

// ---------------- launch ----------------

extern "C" void kernel_launch(void* const* d_in, const int* in_sizes, int n_in,
                              void* d_out, int out_size, void* d_ws, size_t ws_size,
                              hipStream_t stream) {
    const float* x_sent = (const float*)d_in[0];
    const float* x_doc  = (const float*)d_in[1];
    const float* coeff1 = (const float*)d_in[2];
    const float* basis1 = (const float*)d_in[3];
    const float* loopw1 = (const float*)d_in[4];
    const float* bias1  = (const float*)d_in[5];
    const float* coeff2 = (const float*)d_in[6];
    const float* basis2 = (const float*)d_in[7];
    const float* loopw2 = (const float*)d_in[8];
    const float* bias2  = (const float*)d_in[9];
    const float* wscore = (const float*)d_in[10];
    const float* bscore = (const float*)d_in[11];
    const int* src_ss = (const int*)d_in[12];
    const int* dst_ss = (const int*)d_in[13];
    const int* src_sd = (const int*)d_in[14];
    const int* dst_sd = (const int*)d_in[15];
    const int* src_ds = (const int*)d_in[16];
    const int* dst_ds = (const int*)d_in[17];
    const int* gid_sent = (const int*)d_in[18];
    const int* gid_doc  = (const int*)d_in[19];

    const int DIN = 768, DH = 256, DOo = 128;
    const int NS = in_sizes[0] / DIN;     // 100000
    const int ND = in_sizes[1] / DIN;     // 10000
    const int E_SS = in_sizes[12], E_SD = in_sizes[14], E_DS = in_sizes[16];
    const int NTOT = NS + NS + ND;
    const int ETOT = E_SS + E_DS + E_SD;
    const int G = out_size;
    float* out = (float*)d_out;

    char* base = (char*)d_ws;
    size_t off = 0;
    auto alloc = [&](size_t bytes) -> char* {
        char* p = base + off;
        off = (off + bytes + 255) & ~(size_t)255;
        return p;
    };
    ushort* B1sT = (ushort*)alloc((size_t)768 * 768 * 2);
    ushort* B1dT = (ushort*)alloc((size_t)512 * 768 * 2);
    ushort* B2sT = (ushort*)alloc((size_t)384 * 256 * 2);
    ushort* B2dT = (ushort*)alloc((size_t)256 * 256 * 2);
    ushort* ys1 = (ushort*)alloc((size_t)NS * 768 * 2);
    ushort* yd1 = (ushort*)alloc((size_t)ND * 512 * 2);
    ushort* h1s = (ushort*)alloc((size_t)NS * 256 * 2);
    ushort* h1d = (ushort*)alloc((size_t)ND * 256 * 2);
    ushort* ys2 = (ushort*)alloc((size_t)NS * 384 * 2);
    ushort* yd2 = (ushort*)alloc((size_t)ND * 256 * 2);
    int* deg  = (int*)alloc((size_t)2 * NTOT * 4);
    int* fill = deg + NTOT;
    int* rowptr = (int*)alloc((size_t)(NTOT + 1) * 4);
    int* bsum = (int*)alloc(256 * 4);
    int* colall = (int*)alloc((size_t)ETOT * 4);

    // ---- weights (1 kernel per layer, 5 sections each) ----
    long long t1 = (long long)768 * DH, t2 = (long long)256 * DOo;
    fill_w5<<<dim3((unsigned)CDIV(t1, 256), 5), 256, 0, stream>>>(B1sT, B1dT, basis1, loopw1, coeff1, 768, DH, t1);
    fill_w5<<<dim3((unsigned)CDIV(t2, 256), 5), 256, 0, stream>>>(B2sT, B2dT, basis2, loopw2, coeff2, 256, DOo, t2);

    // ---- CSR build ----
    zero_f4<<<(int)CDIV(2 * NTOT / 4, 256), 256, 0, stream>>>((float4*)deg, 2 * NTOT / 4);
    accum_deg_all<<<CDIV(ETOT, 256), 256, 0, stream>>>(dst_ss, dst_ds, dst_sd, E_SS, E_DS, E_SD, NS, deg);
    int nb = CDIV(NTOT, 1024);
    scan_p1<<<nb, 256, 0, stream>>>(deg, NTOT, bsum);
    scan_p2<<<1, 256, 0, stream>>>(bsum, nb, rowptr, NTOT, ETOT);
    scan_p3<<<nb, 256, 0, stream>>>(deg, NTOT, bsum, rowptr);
    fill_csr_all<<<CDIV(ETOT, 256), 256, 0, stream>>>(src_ss, dst_ss, src_ds, dst_ds, src_sd, dst_sd,
                                                      E_SS, E_DS, E_SD, NS, rowptr, fill, colall);

    // ---- layer 1 GEMMs: A is f32 (conversion fused), XCD-swizzled 1-D grid ----
    {
        int mb = CDIV(NS, 128), mb0 = mb / 2;
        int M0 = mb0 * 128;
        gemm_any<true><<<6 * mb0, 256, 0, stream>>>(x_sent, B1sT, ys1, M0, 768, 768, 6);
        gemm_any<true><<<6 * (mb - mb0), 256, 0, stream>>>(
            x_sent + (size_t)M0 * 768, B1sT, ys1 + (size_t)M0 * 768, NS - M0, 768, 768, 6);
    }
    gemm_any<true><<<4 * CDIV(ND, 128), 256, 0, stream>>>(x_doc, B1dT, yd1, ND, 768, 512, 4);

    gather_l1<<<CDIV(NS + ND, 4), 256, 0, stream>>>(ys1, yd1, rowptr, colall, bias1, h1s, h1d, NS, ND);

    // ---- layer 2 (A is bf16, pre-swizzled by gather_l1) ----
    gemm_any<false><<<3 * CDIV(NS, 128), 256, 0, stream>>>(h1s, B2sT, ys2, NS, 256, 384, 3);
    gemm_any<false><<<2 * CDIV(ND, 128), 256, 0, stream>>>(h1d, B2dT, yd2, ND, 256, 256, 2);

    init_out<<<1, 64, 0, stream>>>(out, bscore, G);
    gather_l2<<<1100, 256, 0, stream>>>(ys2, yd2, rowptr, colall, bias2, wscore,
                                        gid_sent, gid_doc, out, NS, ND, G);
}